// Round 7
// baseline (259.386 us; speedup 1.0000x reference)
//
#include <hip/hip_runtime.h>

typedef __bf16 bf16_t;
typedef __bf16 bf16x2 __attribute__((ext_vector_type(2)));
typedef __bf16 bf16x4 __attribute__((ext_vector_type(4)));
typedef __bf16 bf16x8 __attribute__((ext_vector_type(8)));
typedef float f32x4 __attribute__((ext_vector_type(4)));
typedef unsigned int u32x4 __attribute__((ext_vector_type(4)));

#define MFMA16(a, b, c) __builtin_amdgcn_mfma_f32_16x16x32_bf16(a, b, c, 0, 0, 0)
#define LOG2E 1.4426950408889634f
#define SHIFT 16.0f

// async global -> LDS, 16B per lane (LDS dest = wave-uniform base + lane*16)
#define GLL(g, l)                                                      \
  __builtin_amdgcn_global_load_lds(                                    \
      (const __attribute__((address_space(1))) void*)(g),              \
      (__attribute__((address_space(3))) void*)(l), 16, 0, 0)

// raw barrier: wait in-flight GLLs, then s_barrier without compiler drain.
#define WAIT_BARRIER_V0() asm volatile("s_waitcnt vmcnt(0)\n\ts_barrier" ::: "memory")

static constexpr int NB = 2;
static constexpr int SEQ = 4096;
static constexpr int DM = 512;
static constexpr int NH = 8;
static constexpr int HD = 64;
static constexpr int M_ROWS = NB * SEQ;  // 8192

// ---------------------------------------------------------------------------
// Weights fp32 -> bf16
// ---------------------------------------------------------------------------
__global__ __launch_bounds__(256) void cvt_w_kernel(
    const float* __restrict__ w0, const float* __restrict__ w1,
    const float* __restrict__ w2, const float* __restrict__ w3,
    bf16_t* __restrict__ out) {
  const float* src = (blockIdx.y == 0) ? w0 : (blockIdx.y == 1) ? w1
                   : (blockIdx.y == 2) ? w2 : w3;
  int i = (blockIdx.x * 256 + threadIdx.x) * 4;
  float4 v = *(const float4*)(src + i);
  bf16_t* o = out + blockIdx.y * (DM * DM) + i;
  o[0] = (bf16_t)v.x; o[1] = (bf16_t)v.y; o[2] = (bf16_t)v.z; o[3] = (bf16_t)v.w;
}

// ---------------------------------------------------------------------------
// Inputs q,k,v fp32 -> bf16 (fused)
// ---------------------------------------------------------------------------
__global__ __launch_bounds__(256) void cvt_x_kernel(
    const float* __restrict__ q, const float* __restrict__ k,
    const float* __restrict__ v, bf16_t* __restrict__ out) {
  const float* src = (blockIdx.y == 0) ? q : (blockIdx.y == 1) ? k : v;
  bf16_t* dst = out + (size_t)blockIdx.y * (M_ROWS * DM);
  int i = (blockIdx.x * 256 + threadIdx.x) * 8;
  float4 a = *(const float4*)(src + i);
  float4 b = *(const float4*)(src + i + 4);
  bf16x8 o;
  o[0] = (bf16_t)a.x; o[1] = (bf16_t)a.y; o[2] = (bf16_t)a.z; o[3] = (bf16_t)a.w;
  o[4] = (bf16_t)b.x; o[5] = (bf16_t)b.y; o[6] = (bf16_t)b.z; o[7] = (bf16_t)b.w;
  *(bf16x8*)(dst + i) = o;
}

// ---------------------------------------------------------------------------
// GEMM v5: 128x128 tile, BK=64, 2-stage LDS (64KB), stage-after-barrier with
// prefetch depth 1 (v10-attn proven pattern). Per wave: 64x64 quadrant,
// 32 MFMA per K-step from 8 ds_read_b128 per kd (MFMA:read 2.0, was 1.33);
// staged bytes/MFMA 250 (was 375). XOR-swizzled LDS (16B chunks,
// phys = ch ^ (row&7)) -- staging/read/epilogue code identical to v4.
// omode 0: bf16 [bh][s][64]; 1: bf16 [bh][d][s]; 2: fp32 [m][512].
// ---------------------------------------------------------------------------
__device__ __forceinline__ void gemm_body128(
    const bf16_t* __restrict__ X, const bf16_t* __restrict__ Wm,
    const float* __restrict__ bias, void* __restrict__ Out,
    int omode, float scale) {
  __shared__ bf16_t Asm[2][128 * 64];
  __shared__ bf16_t Bsm[2][128 * 64];

  const int tid = threadIdx.x;
  const int w = tid >> 6;
  const int lane = tid & 63;
  const int quad = lane >> 4, l15 = lane & 15;
  const int l8 = lane >> 3;
  const int swcol = ((lane & 7) ^ l8) * 8;  // swizzled source col (elems)
  const int m0 = blockIdx.x * 128;
  const int n0 = blockIdx.y * 128;
  const int moff = (w & 1) * 64;
  const int noff = (w >> 1) * 64;

  f32x4 acc[4][4];
#pragma unroll
  for (int mb = 0; mb < 4; mb++)
#pragma unroll
    for (int nb = 0; nb < 4; nb++) { acc[mb][nb][0] = 0.f; acc[mb][nb][1] = 0.f; acc[mb][nb][2] = 0.f; acc[mb][nb][3] = 0.f; }

  // stage K-step ks into LDS buffer bufi (8 GLLs per thread: 4 B + 4 A)
  auto stage = [&](int ks, int bufi) {
    const int k0 = ks * 64;
#pragma unroll
    for (int j = 0; j < 4; j++) {
      const int row = j * 32 + w * 8 + l8;
      GLL(Wm + (size_t)(n0 + row) * DM + k0 + swcol, &Bsm[bufi][(j * 256 + w * 64) * 8]);
      GLL(X + (size_t)(m0 + row) * DM + k0 + swcol, &Asm[bufi][(j * 256 + w * 64) * 8]);
    }
  };

  stage(0, 0);

  for (int ks = 0; ks < 8; ks++) {
    WAIT_BARRIER_V0();             // tile ks landed; all waves done reading ks-1
    if (ks + 1 < 8) stage(ks + 1, (ks + 1) & 1);   // overwrites ks-1's buffer
    const int p = ks & 1;

#pragma unroll
    for (int kd = 0; kd < 2; kd++) {
      const int fch = (((kd << 2) + quad) ^ (l15 & 7)) << 3;
      bf16x8 bfr[4], afr[4];
#pragma unroll
      for (int nb = 0; nb < 4; nb++)
        bfr[nb] = *(const bf16x8*)&Bsm[p][(noff + nb * 16 + l15) * 64 + fch];
#pragma unroll
      for (int mb = 0; mb < 4; mb++)
        afr[mb] = *(const bf16x8*)&Asm[p][(moff + mb * 16 + l15) * 64 + fch];
#pragma unroll
      for (int mb = 0; mb < 4; mb++)
#pragma unroll
        for (int nb = 0; nb < 4; nb++)
          acc[mb][nb] = MFMA16(afr[mb], bfr[nb], acc[mb][nb]);
    }
  }

  // ---- epilogue ----
#pragma unroll
  for (int nb = 0; nb < 4; nb++) {
    const int n = n0 + noff + nb * 16 + l15;
    const float bn = bias[n];
    const int h = n >> 6, dd = n & 63;
#pragma unroll
    for (int mb = 0; mb < 4; mb++) {
      const int mbase = m0 + moff + mb * 16 + quad * 4;
      const int bb = mbase >> 12, s = mbase & 4095;
      if (omode == 0) {
#pragma unroll
        for (int r = 0; r < 4; r++) {
          const float val = (acc[mb][nb][r] + bn) * scale;
          ((bf16_t*)Out)[(size_t)((bb * NH + h) * SEQ + s + r) * HD + dd] = (bf16_t)val;
        }
      } else if (omode == 1) {
        bf16x4 pk;
#pragma unroll
        for (int r = 0; r < 4; r++) pk[r] = (bf16_t)(acc[mb][nb][r] + bn);
        *(bf16x4*)&((bf16_t*)Out)[(((size_t)(bb * NH + h) * HD + dd) << 12) + s] = pk;
      } else {
#pragma unroll
        for (int r = 0; r < 4; r++)
          ((float*)Out)[(size_t)(mbase + r) * DM + n] = acc[mb][nb][r] + bn;
      }
    }
  }
}

// Fused QKV projection (bf16 inputs). Grid (64,4,3).
__global__ __launch_bounds__(256, 2) void qkv_kernel(
    const bf16_t* __restrict__ Xall, const bf16_t* __restrict__ Wall,
    const float* __restrict__ bq, const float* __restrict__ bk,
    const float* __restrict__ bv, bf16_t* __restrict__ Qb,
    bf16_t* __restrict__ Kb, bf16_t* __restrict__ Vb, float qscale) {
  const int z = blockIdx.z;
  const bf16_t* X = Xall + (size_t)z * (M_ROWS * DM);
  const float* bias = (z == 0) ? bq : (z == 1) ? bk : bv;
  bf16_t* Out = (z == 0) ? Qb : (z == 1) ? Kb : Vb;
  gemm_body128(X, Wall + (size_t)z * DM * DM, bias, Out,
               (z == 2) ? 1 : 0, (z == 0) ? qscale : 1.0f);
}

// Output projection. Grid (64,4).
__global__ __launch_bounds__(256, 2) void oproj_kernel(
    const bf16_t* __restrict__ X, const bf16_t* __restrict__ Wm,
    const float* __restrict__ bias, float* __restrict__ Out) {
  gemm_body128(X, Wm, bias, Out, 2, 1.0f);
}

// ---------------------------------------------------------------------------
// Flash attention v10s: identical to v10 (64q blocks, 2-stage 32KB LDS,
// 2x2 wave split, in-register P redistribution) but launched as TWO
// half-grid dispatches (glob_base 0 / 512) so each dispatch is ~50us --
// lets the GEMM kernels surface in rocprof's top-5 (profiling instrument,
// cost ~3-5us of tail).
// ---------------------------------------------------------------------------
__global__ __launch_bounds__(256, 4) void attn_kernel(
    const bf16_t* __restrict__ Qb, const bf16_t* __restrict__ Kb,
    const bf16_t* __restrict__ Vb, const float* __restrict__ rel_pos,
    bf16_t* __restrict__ attn_out, int glob_base) {
  __shared__ bf16_t Kt[2][64 * 64];    // swizzled [kk][d], 2-stage
  __shared__ bf16_t Vt[2][64 * 64];    // swizzled [d][kk], 2-stage

  const int tid = threadIdx.x;
  const int w = tid >> 6;
  const int lane = tid & 63;
  const int quad = lane >> 4, l15 = lane & 15;
  const int wq = w >> 1, wk = w & 1;

  // XCD swizzle within the half: 512 blocks -> 64 consecutive per XCD
  const int lin = blockIdx.x;
  const int glob = glob_base + (lin & 7) * 64 + (lin >> 3);
  const int bh = glob >> 6;
  const int qb = glob & 63;        // 64-q block
  const int b = bh >> 3, h = bh & 7;
  const int qlo = qb * 64 + wq * 32;   // wave's 32-q base

  const float rb0 = rel_pos[h * 5 + 0] * LOG2E;
  const float rb1 = rel_pos[h * 5 + 1] * LOG2E;
  const float rb2 = rel_pos[h * 5 + 2] * LOG2E;
  const float rb3 = rel_pos[h * 5 + 3] * LOG2E;
  const float rb4 = rel_pos[h * 5 + 4] * LOG2E;

  // Q fragments (B-operand): two q-groups of 16
  bf16x8 qf[2][2];
#pragma unroll
  for (int mb = 0; mb < 2; mb++)
#pragma unroll
    for (int kd = 0; kd < 2; kd++)
      qf[mb][kd] = *(const bf16x8*)(Qb + (size_t)(bh * SEQ + qlo + mb * 16 + l15) * HD + kd * 32 + 8 * quad);

  f32x4 o[2][4];
#pragma unroll
  for (int mb = 0; mb < 2; mb++)
#pragma unroll
    for (int db = 0; db < 4; db++) { o[mb][db][0] = 0.f; o[mb][db][1] = 0.f; o[mb][db][2] = 0.f; o[mb][db][3] = 0.f; }
  f32x4 l4[2];
  l4[0][0] = 0.f; l4[0][1] = 0.f; l4[0][2] = 0.f; l4[0][3] = 0.f;
  l4[1][0] = 0.f; l4[1][1] = 0.f; l4[1][2] = 0.f; l4[1][3] = 0.f;

  bf16x8 ones;
#pragma unroll
  for (int i = 0; i < 8; i++) ones[i] = (bf16_t)1.0f;

  // --- staging addresses (swizzled): phys chunk = logical ^ (row&7)
  const int srow = (w << 4) + (lane >> 3);
  const int scol = (((lane & 7) ^ (lane >> 3)) << 3);
  const bf16_t* kg0 = Kb + ((size_t)(bh * SEQ + srow) << 6) + scol;
  const bf16_t* vg0 = Vb + (((size_t)(bh * HD + srow)) << 12) + scol;
  const int ldst = (w << 10);  // wave's LDS dest (elems)

  // --- fragment read bases (swizzled)
  const int sw = l15 & 7;
  const int kfo0 = (l15 << 6) + ((quad ^ sw) << 3);             // d-half 0
  const int kfo1 = (l15 << 6) + (((quad + 4) ^ sw) << 3);       // d-half 1
  // V fragment: logical kk-chunk = wk*4 + quad
  const int vfo = (l15 << 6) + ((((wk << 2) + quad) ^ sw) << 3);
  const int wk2 = wk << 1;     // row-block base for K reads (wk half)

  auto stage = [&](int t, int bufi) {
    GLL(kg0 + ((size_t)t << 12), &Kt[bufi][ldst]);
    GLL(kg0 + ((size_t)t << 12) + (8 << 6), &Kt[bufi][ldst + 512]);
    GLL(vg0 + (t << 6), &Vt[bufi][ldst]);
    GLL(vg0 + (t << 6) + (8 << 12), &Vt[bufi][ldst + 512]);
  };

  // prologue: stage tile 0
  stage(0, 0);

  for (int t = 0; t < 64; t++) {
    WAIT_BARRIER_V0();             // tile t landed; all reads of t-1 done
    if (t + 1 < 64) stage(t + 1, (t + 1) & 1);
    const int p = t & 1;
    const int klo = t * 64 + wk * 32;

    // ---- tile class: fold bias const + fixed shift into acc init ----
    float cini;
    bool nearband = false;
    if (klo >= qlo + 33)        cini = rb4 - SHIFT;
    else if (klo <= qlo - 33)   cini = rb0 - SHIFT;
    else                        { cini = -SHIFT; nearband = true; }

    // ---- S^T = K.Q^T on wave's 32-kk slice ----
    f32x4 s[2][2];
#pragma unroll
    for (int mb = 0; mb < 2; mb++)
#pragma unroll
      for (int kb = 0; kb < 2; kb++) { s[mb][kb][0] = cini; s[mb][kb][1] = cini; s[mb][kb][2] = cini; s[mb][kb][3] = cini; }
    __builtin_amdgcn_s_setprio(1);
#pragma unroll
    for (int kb = 0; kb < 2; kb++) {
      bf16x8 kA0 = *(const bf16x8*)&Kt[p][kfo0 + ((wk2 + kb) << 10)];
      bf16x8 kA1 = *(const bf16x8*)&Kt[p][kfo1 + ((wk2 + kb) << 10)];
      s[0][kb] = MFMA16(kA0, qf[0][0], s[0][kb]);
      s[0][kb] = MFMA16(kA1, qf[0][1], s[0][kb]);
      s[1][kb] = MFMA16(kA0, qf[1][0], s[1][kb]);
      s[1][kb] = MFMA16(kA1, qf[1][1], s[1][kb]);
    }
    __builtin_amdgcn_s_setprio(0);

    if (nearband) {
#pragma unroll
      for (int mb = 0; mb < 2; mb++) {
        const int qg = qlo + mb * 16 + l15;
#pragma unroll
        for (int kb = 0; kb < 2; kb++)
#pragma unroll
          for (int r = 0; r < 4; r++) {
            int dl = klo + kb * 16 + quad * 4 + r - qg;
            float bias = dl <= -2 ? rb0
                       : (dl >= 2 ? rb4
                       : (dl == -1 ? rb1 : (dl == 0 ? rb2 : rb3)));
            s[mb][kb][r] += bias;
          }
      }
    }

    // ---- p = exp2(s) -> bf16 pack -> in-register redistribution ----
    bf16x8 pf[2];
#pragma unroll
    for (int mb = 0; mb < 2; mb++) {
      unsigned int u[2][2];
#pragma unroll
      for (int kb = 0; kb < 2; kb++) {
        bf16x2 p0, p1;
        p0[0] = (bf16_t)__builtin_amdgcn_exp2f(s[mb][kb][0]);
        p0[1] = (bf16_t)__builtin_amdgcn_exp2f(s[mb][kb][1]);
        p1[0] = (bf16_t)__builtin_amdgcn_exp2f(s[mb][kb][2]);
        p1[1] = (bf16_t)__builtin_amdgcn_exp2f(s[mb][kb][3]);
        u[kb][0] = __builtin_bit_cast(unsigned int, p0);
        u[kb][1] = __builtin_bit_cast(unsigned int, p1);
      }
      unsigned int a0 = u[0][0], b0 = u[1][0];
      unsigned int a1 = u[0][1], b1 = u[1][1];
      asm("v_permlane32_swap_b32 %0, %1" : "+v"(a0), "+v"(b0));
      asm("v_permlane32_swap_b32 %0, %1" : "+v"(a1), "+v"(b1));
      asm("v_permlane16_swap_b32 %0, %1" : "+v"(a0), "+v"(b0));
      asm("v_permlane16_swap_b32 %0, %1" : "+v"(a1), "+v"(b1));
      u32x4 pk; pk[0] = a0; pk[1] = a1; pk[2] = b0; pk[3] = b1;
      pf[mb] = __builtin_bit_cast(bf16x8, pk);
    }

    // ---- l via ones-MFMA, partial O^T += V^T.P^T ----
    __builtin_amdgcn_s_setprio(1);
    l4[0] = MFMA16(ones, pf[0], l4[0]);
    l4[1] = MFMA16(ones, pf[1], l4[1]);
#pragma unroll
    for (int db = 0; db < 4; db++) {
      bf16x8 vA = *(const bf16x8*)&Vt[p][vfo + (db << 10)];
      o[0][db] = MFMA16(vA, pf[0], o[0][db]);
      o[1][db] = MFMA16(vA, pf[1], o[1][db]);
    }
    __builtin_amdgcn_s_setprio(0);
  }

  // ---- cross-wave (wk) reduction of partial O,l via LDS, then epilogue ----
  asm volatile("s_waitcnt vmcnt(0)" ::: "memory");
  __syncthreads();
  float* Ored = (float*)&Kt[0][0];   // 2 x 8KB (per wq) = 16KB
  float* lred = (float*)&Vt[0][0];   // 2 x 128B
  if (wk) {
#pragma unroll
    for (int mb = 0; mb < 2; mb++) {
      lred[(wq << 5) + (mb << 4) + l15] = l4[mb][0];
#pragma unroll
      for (int db = 0; db < 4; db++) {
        const int ch = ((db << 2) | quad) ^ sw;
        *(f32x4*)&Ored[(wq << 11) + ((mb * 16 + l15) << 6) + (ch << 2)] = o[mb][db];
      }
    }
  }
  __syncthreads();
  if (!wk) {
#pragma unroll
    for (int mb = 0; mb < 2; mb++) {
      float lsum = l4[mb][0] + lred[(wq << 5) + (mb << 4) + l15];
      const float inv = 1.0f / lsum;
      const int qg = qlo + mb * 16 + l15;
#pragma unroll
      for (int db = 0; db < 4; db++) {
        const int ch = ((db << 2) | quad) ^ sw;
        const f32x4 part = *(const f32x4*)&Ored[(wq << 11) + ((mb * 16 + l15) << 6) + (ch << 2)];
        bf16x4 pk;
#pragma unroll
        for (int r = 0; r < 4; r++) pk[r] = (bf16_t)((o[mb][db][r] + part[r]) * inv);
        *(bf16x4*)(attn_out + (size_t)(b * SEQ + qg) * DM + h * HD + db * 16 + quad * 4) = pk;
      }
    }
  }
}

// ---------------------------------------------------------------------------
extern "C" void kernel_launch(void* const* d_in, const int* in_sizes, int n_in,
                              void* d_out, int out_size, void* d_ws, size_t ws_size,
                              hipStream_t stream) {
  const float* q   = (const float*)d_in[0];
  const float* k   = (const float*)d_in[1];
  const float* v   = (const float*)d_in[2];
  const float* Wq  = (const float*)d_in[3];
  const float* bq  = (const float*)d_in[4];
  const float* Wk  = (const float*)d_in[5];
  const float* bk  = (const float*)d_in[6];
  const float* Wv  = (const float*)d_in[7];
  const float* bv  = (const float*)d_in[8];
  const float* Wo  = (const float*)d_in[9];
  const float* bo  = (const float*)d_in[10];
  const float* rel = (const float*)d_in[11];

  char* ws = (char*)d_ws;
  bf16_t* Wbf  = (bf16_t*)ws;                               // 2MB (4 matrices)
  bf16_t* Xb   = (bf16_t*)(ws + (size_t)(2  << 20));        // 24MB bf16 q,k,v
  bf16_t* Qbuf = (bf16_t*)(ws + (size_t)(26 << 20));        // 8MB [bh][s][64]
  bf16_t* Kbuf = (bf16_t*)(ws + (size_t)(34 << 20));        // 8MB [bh][s][64]
  bf16_t* Vbuf = (bf16_t*)(ws + (size_t)(42 << 20));        // 8MB [bh][d][s]
  bf16_t* Abuf = (bf16_t*)(ws + (size_t)(2  << 20));        // alias Xb (dead after qkv)

  cvt_w_kernel<<<dim3(256, 4), 256, 0, stream>>>(Wq, Wk, Wv, Wo, Wbf);
  cvt_x_kernel<<<dim3(2048, 3), 256, 0, stream>>>(q, k, v, Xb);

  const float qscale = LOG2E / 8.0f;  // fold 1/sqrt(64) + exp2 domain
  qkv_kernel<<<dim3(64, 4, 3), 256, 0, stream>>>(
      Xb, Wbf, bq, bk, bv, Qbuf, Kbuf, Vbuf, qscale);

  attn_kernel<<<512, 256, 0, stream>>>(Qbuf, Kbuf, Vbuf, rel, Abuf, 0);
  attn_kernel<<<512, 256, 0, stream>>>(Qbuf, Kbuf, Vbuf, rel, Abuf, 512);

  oproj_kernel<<<dim3(64, 4), 256, 0, stream>>>(Abuf, Wbf + 3 * DM * DM, bo, (float*)d_out);
}

// Round 8
// 230.719 us; speedup vs baseline: 1.1242x; 1.1242x over previous
//
#include <hip/hip_runtime.h>

typedef __bf16 bf16_t;
typedef __bf16 bf16x2 __attribute__((ext_vector_type(2)));
typedef __bf16 bf16x4 __attribute__((ext_vector_type(4)));
typedef __bf16 bf16x8 __attribute__((ext_vector_type(8)));
typedef float f32x4 __attribute__((ext_vector_type(4)));
typedef unsigned int u32x4 __attribute__((ext_vector_type(4)));

#define MFMA16(a, b, c) __builtin_amdgcn_mfma_f32_16x16x32_bf16(a, b, c, 0, 0, 0)
#define LOG2E 1.4426950408889634f
#define SHIFT 16.0f

// async global -> LDS, 16B per lane (LDS dest = wave-uniform base + lane*16)
#define GLL(g, l)                                                      \
  __builtin_amdgcn_global_load_lds(                                    \
      (const __attribute__((address_space(1))) void*)(g),              \
      (__attribute__((address_space(3))) void*)(l), 16, 0, 0)

// raw barrier: wait in-flight GLLs + LDS ops, then s_barrier.
#define WAIT_BARRIER_V0() asm volatile("s_waitcnt vmcnt(0)\n\ts_barrier" ::: "memory")
#define WAIT_BARRIER_V0L() asm volatile("s_waitcnt vmcnt(0) lgkmcnt(0)\n\ts_barrier" ::: "memory")
#define WAIT_V4() asm volatile("s_waitcnt vmcnt(4)" ::: "memory")

static constexpr int NB = 2;
static constexpr int SEQ = 4096;
static constexpr int DM = 512;
static constexpr int NH = 8;
static constexpr int HD = 64;
static constexpr int M_ROWS = NB * SEQ;  // 8192

// ---------------------------------------------------------------------------
// Weights fp32 -> bf16
// ---------------------------------------------------------------------------
__global__ __launch_bounds__(256) void cvt_w_kernel(
    const float* __restrict__ w0, const float* __restrict__ w1,
    const float* __restrict__ w2, const float* __restrict__ w3,
    bf16_t* __restrict__ out) {
  const float* src = (blockIdx.y == 0) ? w0 : (blockIdx.y == 1) ? w1
                   : (blockIdx.y == 2) ? w2 : w3;
  int i = (blockIdx.x * 256 + threadIdx.x) * 4;
  float4 v = *(const float4*)(src + i);
  bf16_t* o = out + blockIdx.y * (DM * DM) + i;
  o[0] = (bf16_t)v.x; o[1] = (bf16_t)v.y; o[2] = (bf16_t)v.z; o[3] = (bf16_t)v.w;
}

// ---------------------------------------------------------------------------
// GEMM v6: 128x128 tile, BK=64, 2-stage LDS (64KB), stage-after-barrier with
// prefetch depth 1. template<A32>: A-operand staged either via GLL (bf16
// input) or via reg-staging with fused fp32->bf16 conversion (T14 split:
// issue loads after barrier, convert+ds_write after compute, so HBM latency
// hides under the MFMAs). Eliminates the separate cvt_x pass for qkv.
// XOR-swizzled LDS (16B chunks, phys = ch ^ (row&7)).
// omode 0: bf16 [bh][s][64]; 1: bf16 [bh][d][s]; 2: fp32 [m][512].
// ---------------------------------------------------------------------------
template <bool A32>
__device__ __forceinline__ void gemm_body128(
    const void* __restrict__ Xv, const bf16_t* __restrict__ Wm,
    const float* __restrict__ bias, void* __restrict__ Out,
    int omode, float scale) {
  __shared__ bf16_t Asm[2][128 * 64];
  __shared__ bf16_t Bsm[2][128 * 64];

  const bf16_t* X16 = (const bf16_t*)Xv;
  const float*  X32 = (const float*)Xv;

  const int tid = threadIdx.x;
  const int w = tid >> 6;
  const int lane = tid & 63;
  const int quad = lane >> 4, l15 = lane & 15;
  const int l8 = lane >> 3;
  const int swcol = ((lane & 7) ^ l8) * 8;  // swizzled source col (elems)
  const int m0 = blockIdx.x * 128;
  const int n0 = blockIdx.y * 128;
  const int moff = (w & 1) * 64;
  const int noff = (w >> 1) * 64;

  f32x4 acc[4][4];
#pragma unroll
  for (int mb = 0; mb < 4; mb++)
#pragma unroll
    for (int nb = 0; nb < 4; nb++) { acc[mb][nb][0] = 0.f; acc[mb][nb][1] = 0.f; acc[mb][nb][2] = 0.f; acc[mb][nb][3] = 0.f; }

  auto stageB = [&](int ks, int bufi) {
    const int k0 = ks * 64;
#pragma unroll
    for (int j = 0; j < 4; j++) {
      const int row = j * 32 + w * 8 + l8;
      GLL(Wm + (size_t)(n0 + row) * DM + k0 + swcol, &Bsm[bufi][(j * 256 + w * 64) * 8]);
    }
  };
  auto stageA16 = [&](int ks, int bufi) {
    const int k0 = ks * 64;
#pragma unroll
    for (int j = 0; j < 4; j++) {
      const int row = j * 32 + w * 8 + l8;
      GLL(X16 + (size_t)(m0 + row) * DM + k0 + swcol, &Asm[bufi][(j * 256 + w * 64) * 8]);
    }
  };

  // A32 path: in-flight fp32 registers (32 VGPR)
  f32x4 a32[4][2];
  auto loadA32 = [&](int ks) {
    const int k0 = ks * 64;
#pragma unroll
    for (int j = 0; j < 4; j++) {
      const float* src = X32 + (size_t)(m0 + j * 32 + w * 8 + l8) * DM + k0 + swcol;
      a32[j][0] = *(const f32x4*)src;
      a32[j][1] = *(const f32x4*)(src + 4);
    }
  };
  auto writeA32 = [&](int bufi) {
#pragma unroll
    for (int j = 0; j < 4; j++) {
      bf16x8 v;
#pragma unroll
      for (int r = 0; r < 4; r++) { v[r] = (bf16_t)a32[j][0][r]; v[4 + r] = (bf16_t)a32[j][1][r]; }
      *(bf16x8*)&Asm[bufi][j * 2048 + w * 512 + lane * 8] = v;
    }
  };

  // prologue: stage tile 0
  if (A32) {
    loadA32(0);
    stageB(0, 0);
    WAIT_V4();       // 8 A-loads landed; 4 B GLLs still in flight
    writeA32(0);
  } else {
    stageA16(0, 0);
    stageB(0, 0);
  }

  for (int ks = 0; ks < 8; ks++) {
    WAIT_BARRIER_V0L();            // tile ks fully in LDS (GLL drained, writes fenced)
    if (ks + 1 < 8) {
      if (A32) {
        loadA32(ks + 1);           // 8 vm
        stageB(ks + 1, (ks + 1) & 1);  // +4 vm = 12
      } else {
        stageA16(ks + 1, (ks + 1) & 1);
        stageB(ks + 1, (ks + 1) & 1);
      }
    }
    const int p = ks & 1;

#pragma unroll
    for (int kd = 0; kd < 2; kd++) {
      const int fch = (((kd << 2) + quad) ^ (l15 & 7)) << 3;
      bf16x8 bfr[4], afr[4];
#pragma unroll
      for (int nb = 0; nb < 4; nb++)
        bfr[nb] = *(const bf16x8*)&Bsm[p][(noff + nb * 16 + l15) * 64 + fch];
#pragma unroll
      for (int mb = 0; mb < 4; mb++)
        afr[mb] = *(const bf16x8*)&Asm[p][(moff + mb * 16 + l15) * 64 + fch];
#pragma unroll
      for (int mb = 0; mb < 4; mb++)
#pragma unroll
        for (int nb = 0; nb < 4; nb++)
          acc[mb][nb] = MFMA16(afr[mb], bfr[nb], acc[mb][nb]);
    }

    if (A32 && ks + 1 < 8) {
      WAIT_V4();                   // A-loads for ks+1 landed (B GLLs flying)
      writeA32((ks + 1) & 1);      // into buffer not being read this iter
    }
  }

  // ---- epilogue ----
#pragma unroll
  for (int nb = 0; nb < 4; nb++) {
    const int n = n0 + noff + nb * 16 + l15;
    const float bn = bias[n];
    const int h = n >> 6, dd = n & 63;
#pragma unroll
    for (int mb = 0; mb < 4; mb++) {
      const int mbase = m0 + moff + mb * 16 + quad * 4;
      const int bb = mbase >> 12, s = mbase & 4095;
      if (omode == 0) {
#pragma unroll
        for (int r = 0; r < 4; r++) {
          const float val = (acc[mb][nb][r] + bn) * scale;
          ((bf16_t*)Out)[(size_t)((bb * NH + h) * SEQ + s + r) * HD + dd] = (bf16_t)val;
        }
      } else if (omode == 1) {
        bf16x4 pk;
#pragma unroll
        for (int r = 0; r < 4; r++) pk[r] = (bf16_t)(acc[mb][nb][r] + bn);
        *(bf16x4*)&((bf16_t*)Out)[(((size_t)(bb * NH + h) * HD + dd) << 12) + s] = pk;
      } else {
#pragma unroll
        for (int r = 0; r < 4; r++)
          ((float*)Out)[(size_t)(mbase + r) * DM + n] = acc[mb][nb][r] + bn;
      }
    }
  }
}

// Fused QKV projection reading fp32 inputs directly (cvt fused). Grid (64,4,3).
__global__ __launch_bounds__(256, 2) void qkv_kernel(
    const float* __restrict__ q, const float* __restrict__ k,
    const float* __restrict__ v, const bf16_t* __restrict__ Wall,
    const float* __restrict__ bq, const float* __restrict__ bk,
    const float* __restrict__ bv, bf16_t* __restrict__ Qb,
    bf16_t* __restrict__ Kb, bf16_t* __restrict__ Vb, float qscale) {
  const int z = blockIdx.z;
  const float* X = (z == 0) ? q : (z == 1) ? k : v;
  const float* bias = (z == 0) ? bq : (z == 1) ? bk : bv;
  bf16_t* Out = (z == 0) ? Qb : (z == 1) ? Kb : Vb;
  gemm_body128<true>((const void*)X, Wall + (size_t)z * DM * DM, bias, Out,
                     (z == 2) ? 1 : 0, (z == 0) ? qscale : 1.0f);
}

// Output projection (bf16 input). Grid (64,4).
__global__ __launch_bounds__(256, 2) void oproj_kernel(
    const bf16_t* __restrict__ X, const bf16_t* __restrict__ Wm,
    const float* __restrict__ bias, float* __restrict__ Out) {
  gemm_body128<false>((const void*)X, Wm, bias, Out, 2, 1.0f);
}

// ---------------------------------------------------------------------------
// Flash attention v10 (reverted to single 1024-block dispatch = 4 blocks/CU;
// round-7 split showed 2/CU costs +29us). 64q blocks, 2-stage 32KB LDS,
// 2x2 wave split, in-register P redistribution, XCD swizzle, cross-wave
// O/l reduction. Grid (1024).
// ---------------------------------------------------------------------------
__global__ __launch_bounds__(256, 4) void attn_kernel(
    const bf16_t* __restrict__ Qb, const bf16_t* __restrict__ Kb,
    const bf16_t* __restrict__ Vb, const float* __restrict__ rel_pos,
    bf16_t* __restrict__ attn_out) {
  __shared__ bf16_t Kt[2][64 * 64];    // swizzled [kk][d], 2-stage
  __shared__ bf16_t Vt[2][64 * 64];    // swizzled [d][kk], 2-stage

  const int tid = threadIdx.x;
  const int w = tid >> 6;
  const int lane = tid & 63;
  const int quad = lane >> 4, l15 = lane & 15;
  const int wq = w >> 1, wk = w & 1;

  // XCD swizzle: 1024 blocks, 8 XCDs -> 128 consecutive per XCD (bijective)
  const int lin = blockIdx.x;
  const int glob = (lin & 7) * 128 + (lin >> 3);
  const int bh = glob >> 6;        // 2 bh per XCD
  const int qb = glob & 63;        // 64-q block
  const int b = bh >> 3, h = bh & 7;
  const int qlo = qb * 64 + wq * 32;   // wave's 32-q base

  const float rb0 = rel_pos[h * 5 + 0] * LOG2E;
  const float rb1 = rel_pos[h * 5 + 1] * LOG2E;
  const float rb2 = rel_pos[h * 5 + 2] * LOG2E;
  const float rb3 = rel_pos[h * 5 + 3] * LOG2E;
  const float rb4 = rel_pos[h * 5 + 4] * LOG2E;

  // Q fragments (B-operand): two q-groups of 16
  bf16x8 qf[2][2];
#pragma unroll
  for (int mb = 0; mb < 2; mb++)
#pragma unroll
    for (int kd = 0; kd < 2; kd++)
      qf[mb][kd] = *(const bf16x8*)(Qb + (size_t)(bh * SEQ + qlo + mb * 16 + l15) * HD + kd * 32 + 8 * quad);

  f32x4 o[2][4];
#pragma unroll
  for (int mb = 0; mb < 2; mb++)
#pragma unroll
    for (int db = 0; db < 4; db++) { o[mb][db][0] = 0.f; o[mb][db][1] = 0.f; o[mb][db][2] = 0.f; o[mb][db][3] = 0.f; }
  f32x4 l4[2];
  l4[0][0] = 0.f; l4[0][1] = 0.f; l4[0][2] = 0.f; l4[0][3] = 0.f;
  l4[1][0] = 0.f; l4[1][1] = 0.f; l4[1][2] = 0.f; l4[1][3] = 0.f;

  bf16x8 ones;
#pragma unroll
  for (int i = 0; i < 8; i++) ones[i] = (bf16_t)1.0f;

  // --- staging addresses (swizzled): phys chunk = logical ^ (row&7)
  const int srow = (w << 4) + (lane >> 3);
  const int scol = (((lane & 7) ^ (lane >> 3)) << 3);
  const bf16_t* kg0 = Kb + ((size_t)(bh * SEQ + srow) << 6) + scol;
  const bf16_t* vg0 = Vb + (((size_t)(bh * HD + srow)) << 12) + scol;
  const int ldst = (w << 10);  // wave's LDS dest (elems)

  // --- fragment read bases (swizzled)
  const int sw = l15 & 7;
  const int kfo0 = (l15 << 6) + ((quad ^ sw) << 3);             // d-half 0
  const int kfo1 = (l15 << 6) + (((quad + 4) ^ sw) << 3);       // d-half 1
  // V fragment: logical kk-chunk = wk*4 + quad
  const int vfo = (l15 << 6) + ((((wk << 2) + quad) ^ sw) << 3);
  const int wk2 = wk << 1;     // row-block base for K reads (wk half)

  auto stage = [&](int t, int bufi) {
    GLL(kg0 + ((size_t)t << 12), &Kt[bufi][ldst]);
    GLL(kg0 + ((size_t)t << 12) + (8 << 6), &Kt[bufi][ldst + 512]);
    GLL(vg0 + (t << 6), &Vt[bufi][ldst]);
    GLL(vg0 + (t << 6) + (8 << 12), &Vt[bufi][ldst + 512]);
  };

  // prologue: stage tile 0
  stage(0, 0);

  for (int t = 0; t < 64; t++) {
    WAIT_BARRIER_V0();             // tile t landed; all reads of t-1 done
    if (t + 1 < 64) stage(t + 1, (t + 1) & 1);
    const int p = t & 1;
    const int klo = t * 64 + wk * 32;

    // ---- tile class: fold bias const + fixed shift into acc init ----
    float cini;
    bool nearband = false;
    if (klo >= qlo + 33)        cini = rb4 - SHIFT;
    else if (klo <= qlo - 33)   cini = rb0 - SHIFT;
    else                        { cini = -SHIFT; nearband = true; }

    // ---- S^T = K.Q^T on wave's 32-kk slice ----
    f32x4 s[2][2];
#pragma unroll
    for (int mb = 0; mb < 2; mb++)
#pragma unroll
      for (int kb = 0; kb < 2; kb++) { s[mb][kb][0] = cini; s[mb][kb][1] = cini; s[mb][kb][2] = cini; s[mb][kb][3] = cini; }
    __builtin_amdgcn_s_setprio(1);
#pragma unroll
    for (int kb = 0; kb < 2; kb++) {
      bf16x8 kA0 = *(const bf16x8*)&Kt[p][kfo0 + ((wk2 + kb) << 10)];
      bf16x8 kA1 = *(const bf16x8*)&Kt[p][kfo1 + ((wk2 + kb) << 10)];
      s[0][kb] = MFMA16(kA0, qf[0][0], s[0][kb]);
      s[0][kb] = MFMA16(kA1, qf[0][1], s[0][kb]);
      s[1][kb] = MFMA16(kA0, qf[1][0], s[1][kb]);
      s[1][kb] = MFMA16(kA1, qf[1][1], s[1][kb]);
    }
    __builtin_amdgcn_s_setprio(0);

    if (nearband) {
#pragma unroll
      for (int mb = 0; mb < 2; mb++) {
        const int qg = qlo + mb * 16 + l15;
#pragma unroll
        for (int kb = 0; kb < 2; kb++)
#pragma unroll
          for (int r = 0; r < 4; r++) {
            int dl = klo + kb * 16 + quad * 4 + r - qg;
            float bias = dl <= -2 ? rb0
                       : (dl >= 2 ? rb4
                       : (dl == -1 ? rb1 : (dl == 0 ? rb2 : rb3)));
            s[mb][kb][r] += bias;
          }
      }
    }

    // ---- p = exp2(s) -> bf16 pack -> in-register redistribution ----
    bf16x8 pf[2];
#pragma unroll
    for (int mb = 0; mb < 2; mb++) {
      unsigned int u[2][2];
#pragma unroll
      for (int kb = 0; kb < 2; kb++) {
        bf16x2 p0, p1;
        p0[0] = (bf16_t)__builtin_amdgcn_exp2f(s[mb][kb][0]);
        p0[1] = (bf16_t)__builtin_amdgcn_exp2f(s[mb][kb][1]);
        p1[0] = (bf16_t)__builtin_amdgcn_exp2f(s[mb][kb][2]);
        p1[1] = (bf16_t)__builtin_amdgcn_exp2f(s[mb][kb][3]);
        u[kb][0] = __builtin_bit_cast(unsigned int, p0);
        u[kb][1] = __builtin_bit_cast(unsigned int, p1);
      }
      unsigned int a0 = u[0][0], b0 = u[1][0];
      unsigned int a1 = u[0][1], b1 = u[1][1];
      asm("v_permlane32_swap_b32 %0, %1" : "+v"(a0), "+v"(b0));
      asm("v_permlane32_swap_b32 %0, %1" : "+v"(a1), "+v"(b1));
      asm("v_permlane16_swap_b32 %0, %1" : "+v"(a0), "+v"(b0));
      asm("v_permlane16_swap_b32 %0, %1" : "+v"(a1), "+v"(b1));
      u32x4 pk; pk[0] = a0; pk[1] = a1; pk[2] = b0; pk[3] = b1;
      pf[mb] = __builtin_bit_cast(bf16x8, pk);
    }

    // ---- l via ones-MFMA, partial O^T += V^T.P^T ----
    __builtin_amdgcn_s_setprio(1);
    l4[0] = MFMA16(ones, pf[0], l4[0]);
    l4[1] = MFMA16(ones, pf[1], l4[1]);
#pragma unroll
    for (int db = 0; db < 4; db++) {
      bf16x8 vA = *(const bf16x8*)&Vt[p][vfo + (db << 10)];
      o[0][db] = MFMA16(vA, pf[0], o[0][db]);
      o[1][db] = MFMA16(vA, pf[1], o[1][db]);
    }
    __builtin_amdgcn_s_setprio(0);
  }

  // ---- cross-wave (wk) reduction of partial O,l via LDS, then epilogue ----
  asm volatile("s_waitcnt vmcnt(0)" ::: "memory");
  __syncthreads();
  float* Ored = (float*)&Kt[0][0];   // 2 x 8KB (per wq) = 16KB
  float* lred = (float*)&Vt[0][0];   // 2 x 128B
  if (wk) {
#pragma unroll
    for (int mb = 0; mb < 2; mb++) {
      lred[(wq << 5) + (mb << 4) + l15] = l4[mb][0];
#pragma unroll
      for (int db = 0; db < 4; db++) {
        const int ch = ((db << 2) | quad) ^ sw;
        *(f32x4*)&Ored[(wq << 11) + ((mb * 16 + l15) << 6) + (ch << 2)] = o[mb][db];
      }
    }
  }
  __syncthreads();
  if (!wk) {
#pragma unroll
    for (int mb = 0; mb < 2; mb++) {
      float lsum = l4[mb][0] + lred[(wq << 5) + (mb << 4) + l15];
      const float inv = 1.0f / lsum;
      const int qg = qlo + mb * 16 + l15;
#pragma unroll
      for (int db = 0; db < 4; db++) {
        const int ch = ((db << 2) | quad) ^ sw;
        const f32x4 part = *(const f32x4*)&Ored[(wq << 11) + ((mb * 16 + l15) << 6) + (ch << 2)];
        bf16x4 pk;
#pragma unroll
        for (int r = 0; r < 4; r++) pk[r] = (bf16_t)((o[mb][db][r] + part[r]) * inv);
        *(bf16x4*)(attn_out + (size_t)(b * SEQ + qg) * DM + h * HD + db * 16 + quad * 4) = pk;
      }
    }
  }
}

// ---------------------------------------------------------------------------
extern "C" void kernel_launch(void* const* d_in, const int* in_sizes, int n_in,
                              void* d_out, int out_size, void* d_ws, size_t ws_size,
                              hipStream_t stream) {
  const float* q   = (const float*)d_in[0];
  const float* k   = (const float*)d_in[1];
  const float* v   = (const float*)d_in[2];
  const float* Wq  = (const float*)d_in[3];
  const float* bq  = (const float*)d_in[4];
  const float* Wk  = (const float*)d_in[5];
  const float* bk  = (const float*)d_in[6];
  const float* Wv  = (const float*)d_in[7];
  const float* bv  = (const float*)d_in[8];
  const float* Wo  = (const float*)d_in[9];
  const float* bo  = (const float*)d_in[10];
  const float* rel = (const float*)d_in[11];

  char* ws = (char*)d_ws;
  bf16_t* Wbf  = (bf16_t*)ws;                               // 2MB (4 matrices)
  bf16_t* Abuf = (bf16_t*)(ws + (size_t)(2  << 20));        // 8MB attn out [m][512]
  bf16_t* Qbuf = (bf16_t*)(ws + (size_t)(26 << 20));        // 8MB [bh][s][64]
  bf16_t* Kbuf = (bf16_t*)(ws + (size_t)(34 << 20));        // 8MB [bh][s][64]
  bf16_t* Vbuf = (bf16_t*)(ws + (size_t)(42 << 20));        // 8MB [bh][d][s]

  cvt_w_kernel<<<dim3(256, 4), 256, 0, stream>>>(Wq, Wk, Wv, Wo, Wbf);

  const float qscale = LOG2E / 8.0f;  // fold 1/sqrt(64) + exp2 domain
  qkv_kernel<<<dim3(64, 4, 3), 256, 0, stream>>>(
      q, k, v, Wbf, bq, bk, bv, Qbuf, Kbuf, Vbuf, qscale);

  attn_kernel<<<1024, 256, 0, stream>>>(Qbuf, Kbuf, Vbuf, rel, Abuf);

  oproj_kernel<<<dim3(64, 4), 256, 0, stream>>>(Abuf, Wbf + 3 * DM * DM, bo, (float*)d_out);
}